// Round 1
// baseline (483.302 us; speedup 1.0000x reference)
//
#include <hip/hip_runtime.h>

#define NN 50000
#define NE 400000
#define INF 768
#define HF 16
#define OF 21

// -----------------------------------------------------------------------------
// GEMM1: P[n][j] = sum_k feature[n][k] * W1[k][j]   (50000 x 768 @ 768 x 16)
// Block = 256 threads (4 waves), 128 rows per block (32 rows per wave).
// Lane layout: q = lane&3 (k-split), jb = (lane>>2)&1 (j half), rg = lane>>3.
// Lane register tile: 4 rows x 8 j, accumulated over its k-quarter; final
// butterfly over q (shfl_xor 1,2) then one writer per row.
// LDS: Fs[128][68] (pad stride 68 floats = 17 float4, odd -> conflict-free),
//      W1s[16][68] transposed chunk.
// -----------------------------------------------------------------------------
__global__ __launch_bounds__(256) void gemm1_kernel(const float* __restrict__ F,
                                                    const float* __restrict__ W1,
                                                    float* __restrict__ P) {
    __shared__ float Fs[128 * 68];
    __shared__ float W1s[16 * 68];

    const int t    = threadIdx.x;
    const int wave = t >> 6;
    const int lane = t & 63;
    const int q    = lane & 3;
    const int jb   = (lane >> 2) & 1;
    const int rg   = lane >> 3;
    const int rowbase = blockIdx.x * 128;

    float acc[4][8];
#pragma unroll
    for (int r = 0; r < 4; ++r)
#pragma unroll
        for (int j = 0; j < 8; ++j) acc[r][j] = 0.0f;

    // precompute (clamped) staging rows for this thread
    int srow[8];
#pragma unroll
    for (int rr = 0; rr < 8; ++rr) {
        int rl = rr * 16 + (t >> 4);
        int row = rowbase + rl;
        srow[rr] = (row < NN) ? row : (NN - 1);
    }
    const int c4 = t & 15;

    for (int kc = 0; kc < 12; ++kc) {   // 12 chunks of 64 k
        __syncthreads();
        // ---- stage feature tile: 128 rows x 64 floats
#pragma unroll
        for (int rr = 0; rr < 8; ++rr) {
            int rl = rr * 16 + (t >> 4);
            float4 v = *(const float4*)(F + (size_t)srow[rr] * INF + kc * 64 + c4 * 4);
            *(float4*)(Fs + rl * 68 + c4 * 4) = v;
        }
        // ---- stage W1 chunk transposed: W1s[j][k_local]
#pragma unroll
        for (int i = 0; i < 4; ++i) {
            int kl = i * 16 + (t >> 4);
            int j  = t & 15;
            W1s[j * 68 + kl] = W1[(kc * 64 + kl) * HF + j];
        }
        __syncthreads();
        // ---- compute: each lane does its k-quarter of this chunk
#pragma unroll
        for (int t4 = 0; t4 < 4; ++t4) {
            const int k4 = t4 * 4 + q;   // float4 index in chunk, 0..15
            float4 f[4], w[8];
#pragma unroll
            for (int r = 0; r < 4; ++r)
                f[r] = *(const float4*)(Fs + (wave * 32 + rg * 4 + r) * 68 + k4 * 4);
#pragma unroll
            for (int j = 0; j < 8; ++j)
                w[j] = *(const float4*)(W1s + (jb * 8 + j) * 68 + k4 * 4);
#pragma unroll
            for (int r = 0; r < 4; ++r)
#pragma unroll
                for (int j = 0; j < 8; ++j)
                    acc[r][j] += f[r].x * w[j].x + f[r].y * w[j].y +
                                 f[r].z * w[j].z + f[r].w * w[j].w;
        }
    }

    // ---- reduce across the 4 k-split lanes (q) : butterfly
#pragma unroll
    for (int r = 0; r < 4; ++r)
#pragma unroll
        for (int j = 0; j < 8; ++j) {
            float v = acc[r][j];
            v += __shfl_xor(v, 1);
            v += __shfl_xor(v, 2);
            acc[r][j] = v;
        }

    // lane q writes row rg*4 + q ; select acc[q][*] without dynamic indexing
    float vsel[8];
#pragma unroll
    for (int j = 0; j < 8; ++j) {
        float a = (q & 1) ? acc[1][j] : acc[0][j];
        float b = (q & 1) ? acc[3][j] : acc[2][j];
        vsel[j] = (q & 2) ? b : a;
    }
    const int row = rowbase + wave * 32 + rg * 4 + q;
    if (row < NN) {
        float4 o0 = make_float4(vsel[0], vsel[1], vsel[2], vsel[3]);
        float4 o1 = make_float4(vsel[4], vsel[5], vsel[6], vsel[7]);
        *(float4*)(P + (size_t)row * HF + jb * 8)     = o0;
        *(float4*)(P + (size_t)row * HF + jb * 8 + 4) = o1;
    }
}

// -----------------------------------------------------------------------------
// Edge aggregation: Y[dst[e]][:] += g(X[src[e]][:])  with optional relu(x+b1).
// 4 threads per edge, each handles a float4 (16 dims total).
// -----------------------------------------------------------------------------
__global__ __launch_bounds__(256) void agg_kernel(const float* __restrict__ X,
                                                  const int* __restrict__ src,
                                                  const int* __restrict__ dst,
                                                  const float* __restrict__ bias,
                                                  float* __restrict__ Y,
                                                  int relu_mode) {
    int t = blockIdx.x * 256 + threadIdx.x;
    if (t >= NE * 4) return;
    const int e    = t >> 2;
    const int part = (t & 3) * 4;
    const int s = src[e];
    const int d = dst[e];
    float4 v = *(const float4*)(X + (size_t)s * HF + part);
    if (relu_mode) {
        float4 b = *(const float4*)(bias + part);
        v.x = fmaxf(v.x + b.x, 0.0f);
        v.y = fmaxf(v.y + b.y, 0.0f);
        v.z = fmaxf(v.z + b.z, 0.0f);
        v.w = fmaxf(v.w + b.w, 0.0f);
    }
    float* yp = Y + (size_t)d * HF + part;
    atomicAdd(yp + 0, v.x);
    atomicAdd(yp + 1, v.y);
    atomicAdd(yp + 2, v.z);
    atomicAdd(yp + 3, v.w);
}

// -----------------------------------------------------------------------------
// Output: out[n][c] = sum_j A2[n][j] * W2[j][c] + b2[c]   (16 -> 21)
// -----------------------------------------------------------------------------
__global__ __launch_bounds__(256) void out_kernel(const float* __restrict__ A2,
                                                  const float* __restrict__ W2,
                                                  const float* __restrict__ b2,
                                                  float* __restrict__ out) {
    __shared__ float W2s[HF * OF];
    __shared__ float b2s[OF];
    const int t = threadIdx.x;
    for (int i = t; i < HF * OF; i += 256) W2s[i] = W2[i];
    if (t < OF) b2s[t] = b2[t];
    __syncthreads();

    const int row = blockIdx.x * 256 + t;
    if (row >= NN) return;

    float a[16];
#pragma unroll
    for (int i = 0; i < 4; ++i)
        *(float4*)(a + i * 4) = *(const float4*)(A2 + (size_t)row * HF + i * 4);

    float o[OF];
#pragma unroll
    for (int c = 0; c < OF; ++c) o[c] = b2s[c];
#pragma unroll
    for (int j = 0; j < HF; ++j) {
        const float aj = a[j];
#pragma unroll
        for (int c = 0; c < OF; ++c) o[c] += aj * W2s[j * OF + c];
    }
    float* op = out + (size_t)row * OF;
#pragma unroll
    for (int c = 0; c < OF; ++c) op[c] = o[c];
}

extern "C" void kernel_launch(void* const* d_in, const int* in_sizes, int n_in,
                              void* d_out, int out_size, void* d_ws, size_t ws_size,
                              hipStream_t stream) {
    const float* F  = (const float*)d_in[0];
    const float* W1 = (const float*)d_in[1];
    const float* b1 = (const float*)d_in[2];
    const float* W2 = (const float*)d_in[3];
    const float* b2 = (const float*)d_in[4];
    const int*   src = (const int*)d_in[5];
    const int*   dst = (const int*)d_in[6];
    float* out = (float*)d_out;

    char* ws = (char*)d_ws;
    float* P  = (float*)(ws);             // 50000*16*4 = 3.2 MB
    float* A1 = (float*)(ws + 3200000);   // 3.2 MB
    float* A2 = (float*)(ws + 6400000);   // 3.2 MB

    // zero the accumulation buffers (ws is poisoned 0xAA before every launch)
    hipMemsetAsync(A1, 0, 3200000, stream);
    hipMemsetAsync(A2, 0, 3200000, stream);

    // P = feature @ W1  (agg and right-multiply commute: segment_sum is linear)
    gemm1_kernel<<<391, 256, 0, stream>>>(F, W1, P);
    // A1 = segment_sum(P[src], dst)
    agg_kernel<<<(NE * 4) / 256, 256, 0, stream>>>(P, src, dst, nullptr, A1, 0);
    // A2 = segment_sum(relu(A1 + b1)[src], dst)
    agg_kernel<<<(NE * 4) / 256, 256, 0, stream>>>(A1, src, dst, b1, A2, 1);
    // out = A2 @ W2 + b2
    out_kernel<<<(NN + 255) / 256, 256, 0, stream>>>(A2, W2, b2, out);
}

// Round 3
// 341.249 us; speedup vs baseline: 1.4163x; 1.4163x over previous
//
#include <hip/hip_runtime.h>

#define NN 50000
#define NE 400000
#define INF 768
#define HF 16
#define OF 21
#define ELLW 40   // Poisson(8) max-degree guard: P(deg>=40)*NN ~ 2e-11

// -----------------------------------------------------------------------------
// Build ELL adjacency: cnt[d] = in-degree, ell[d*ELLW + i] = src of i-th edge
// into d. Int atomics only (returns slot). Order nondeterminism only permutes
// the fp-sum order downstream (within absmax threshold).
// -----------------------------------------------------------------------------
__global__ __launch_bounds__(256) void scatter_kernel(const int* __restrict__ src,
                                                      const int* __restrict__ dst,
                                                      int* __restrict__ cnt,
                                                      int* __restrict__ ell) {
    int e = blockIdx.x * 256 + threadIdx.x;
    if (e >= NE) return;
    int d = dst[e];
    int pos = atomicAdd(&cnt[d], 1);
    if (pos < ELLW) ell[d * ELLW + pos] = src[e];
}

// -----------------------------------------------------------------------------
// GEMM1: P = F @ W1  (50000x768 @ 768x16), pure streaming, no syncthreads in
// the hot loop. W1 in LDS as [j4][k][jj] planes: 48 KB -> 3 blocks/CU,
// 16B-aligned b128 reads; k-split lanes hit banks 2-way only (free).
// 4 lanes per row (k-split by float4), butterfly over q at the end.
// NOTE: macro params must not be named x/y/z/w — the preprocessor substitutes
// them even after a '.', mangling field accesses (round-2 compile failure).
// -----------------------------------------------------------------------------
#define FMA4(ACC, SS, VV) { (ACC).x += (SS)*(VV).x; (ACC).y += (SS)*(VV).y; \
                            (ACC).z += (SS)*(VV).z; (ACC).w += (SS)*(VV).w; }

__global__ __launch_bounds__(256) void gemm1_kernel(const float* __restrict__ F,
                                                    const float* __restrict__ W1,
                                                    float* __restrict__ P) {
    __shared__ float W1v[4 * INF * 4];   // [j4][k][jj], 48 KB

    const int t = threadIdx.x;
    for (int idx = t; idx < INF * HF; idx += 256) {
        int k = idx >> 4, j = idx & 15;
        W1v[(j >> 2) * (INF * 4) + k * 4 + (j & 3)] = W1[idx];
    }
    __syncthreads();

    int row = blockIdx.x * 64 + (t >> 2);
    const int q = t & 3;
    const bool active = row < NN;
    if (!active) row = NN - 1;

    const float* base = F + (size_t)row * INF + q * 4;
    float4 acc0 = {0,0,0,0}, acc1 = {0,0,0,0}, acc2 = {0,0,0,0}, acc3 = {0,0,0,0};

    float4 fa = *(const float4*)(base);
    float4 fb = *(const float4*)(base + 16);

#pragma unroll 4
    for (int i = 0; i < 48; ++i) {
        const int nx = i + 2;
        float4 fc = *(const float4*)(base + 16 * (nx < 48 ? nx : 0));
        const int kb = 16 * i + 4 * q;            // scalar k base of fa
#pragma unroll
        for (int m = 0; m < 4; ++m) {
            const float fm = (m == 0) ? fa.x : (m == 1) ? fa.y : (m == 2) ? fa.z : fa.w;
            const int ko = (kb + m) * 4;
            float4 w0 = *(const float4*)&W1v[0 * (INF * 4) + ko];
            float4 w1 = *(const float4*)&W1v[1 * (INF * 4) + ko];
            float4 w2 = *(const float4*)&W1v[2 * (INF * 4) + ko];
            float4 w3 = *(const float4*)&W1v[3 * (INF * 4) + ko];
            FMA4(acc0, fm, w0);
            FMA4(acc1, fm, w1);
            FMA4(acc2, fm, w2);
            FMA4(acc3, fm, w3);
        }
        fa = fb; fb = fc;
    }

    // butterfly-reduce the 4 k-split lanes (xor 1, 2 stay within the row group)
#define BFLY(VAL) { VAL += __shfl_xor(VAL, 1); VAL += __shfl_xor(VAL, 2); }
    BFLY(acc0.x) BFLY(acc0.y) BFLY(acc0.z) BFLY(acc0.w)
    BFLY(acc1.x) BFLY(acc1.y) BFLY(acc1.z) BFLY(acc1.w)
    BFLY(acc2.x) BFLY(acc2.y) BFLY(acc2.z) BFLY(acc2.w)
    BFLY(acc3.x) BFLY(acc3.y) BFLY(acc3.z) BFLY(acc3.w)
#undef BFLY

    // lane q writes j-chunk q (contiguous 64B across the 4 lanes)
    float4 ov;
    ov.x = (q == 0) ? acc0.x : (q == 1) ? acc1.x : (q == 2) ? acc2.x : acc3.x;
    ov.y = (q == 0) ? acc0.y : (q == 1) ? acc1.y : (q == 2) ? acc2.y : acc3.y;
    ov.z = (q == 0) ? acc0.z : (q == 1) ? acc1.z : (q == 2) ? acc2.z : acc3.z;
    ov.w = (q == 0) ? acc0.w : (q == 1) ? acc1.w : (q == 2) ? acc2.w : acc3.w;
    if (active)
        *(float4*)(P + (size_t)row * HF + q * 4) = ov;
}

// -----------------------------------------------------------------------------
// agg1: A1[n] = sum over incoming edges of P[src]. 4 lanes per node (float4
// each). No atomics, no zero-init needed: every row is written exactly once.
// -----------------------------------------------------------------------------
__global__ __launch_bounds__(256) void agg1_kernel(const float* __restrict__ P,
                                                   const int* __restrict__ cnt,
                                                   const int* __restrict__ ell,
                                                   float* __restrict__ A1) {
    int g = blockIdx.x * 256 + threadIdx.x;
    int node = g >> 2;
    if (node >= NN) return;
    const int q = g & 3;
    int c = cnt[node]; if (c > ELLW) c = ELLW;
    const int* ep = ell + node * ELLW;
    float4 v = {0,0,0,0};
    for (int i = 0; i < c; ++i) {
        int s = ep[i];
        float4 p = *(const float4*)(P + (size_t)s * HF + q * 4);
        v.x += p.x; v.y += p.y; v.z += p.z; v.w += p.w;
    }
    *(float4*)(A1 + (size_t)node * HF + q * 4) = v;
}

// -----------------------------------------------------------------------------
// agg2 + output GEMM fused: A2[n] = sum relu(A1[src] + b1) held in registers
// (4 lanes x float4), then out[n] = A2 @ W2 + b2 via per-lane partials +
// 2-round butterfly. A2 never materialized.
// -----------------------------------------------------------------------------
__global__ __launch_bounds__(256) void agg2out_kernel(const float* __restrict__ A1,
                                                      const float* __restrict__ b1,
                                                      const int* __restrict__ cnt,
                                                      const int* __restrict__ ell,
                                                      const float* __restrict__ W2,
                                                      const float* __restrict__ b2,
                                                      float* __restrict__ out) {
    __shared__ float W2s[HF * OF];
    __shared__ float b2s[OF];
    const int t = threadIdx.x;
    for (int i = t; i < HF * OF; i += 256) W2s[i] = W2[i];
    if (t < OF) b2s[t] = b2[t];
    __syncthreads();

    int g = blockIdx.x * 256 + t;
    int node = g >> 2;
    if (node >= NN) return;
    const int q = g & 3;

    const float4 bb = *(const float4*)(b1 + q * 4);
    int c = cnt[node]; if (c > ELLW) c = ELLW;
    const int* ep = ell + node * ELLW;

    float4 v = {0,0,0,0};
    for (int i = 0; i < c; ++i) {
        int s = ep[i];
        float4 h = *(const float4*)(A1 + (size_t)s * HF + q * 4);
        h.x = fmaxf(h.x + bb.x, 0.0f);
        h.y = fmaxf(h.y + bb.y, 0.0f);
        h.z = fmaxf(h.z + bb.z, 0.0f);
        h.w = fmaxf(h.w + bb.w, 0.0f);
        v.x += h.x; v.y += h.y; v.z += h.z; v.w += h.w;
    }

    // partial out over this lane's 4 hidden dims (j = 4q .. 4q+3)
    const float* w0 = W2s + (q * 4 + 0) * OF;
    const float* w1 = W2s + (q * 4 + 1) * OF;
    const float* w2 = W2s + (q * 4 + 2) * OF;
    const float* w3 = W2s + (q * 4 + 3) * OF;
    float o[OF];
#pragma unroll
    for (int cc = 0; cc < OF; ++cc)
        o[cc] = v.x * w0[cc] + v.y * w1[cc] + v.z * w2[cc] + v.w * w3[cc];
#pragma unroll
    for (int cc = 0; cc < OF; ++cc) {
        o[cc] += __shfl_xor(o[cc], 1);
        o[cc] += __shfl_xor(o[cc], 2);
    }
    float* op = out + (size_t)node * OF;
    for (int cc = q; cc < OF; cc += 4) op[cc] = o[cc] + b2s[cc];
}

extern "C" void kernel_launch(void* const* d_in, const int* in_sizes, int n_in,
                              void* d_out, int out_size, void* d_ws, size_t ws_size,
                              hipStream_t stream) {
    const float* F   = (const float*)d_in[0];
    const float* W1  = (const float*)d_in[1];
    const float* b1  = (const float*)d_in[2];
    const float* W2  = (const float*)d_in[3];
    const float* b2  = (const float*)d_in[4];
    const int*   src = (const int*)d_in[5];
    const int*   dst = (const int*)d_in[6];
    float* out = (float*)d_out;

    char* ws = (char*)d_ws;
    int*   cnt = (int*)(ws);                       // 200,000 B
    int*   ell = (int*)(ws + 200192);              // 8,000,000 B
    float* P   = (float*)(ws + 8200192);           // 3,200,000 B
    float* A1  = (float*)(ws + 11400192);          // 3,200,000 B

    (void)hipMemsetAsync(cnt, 0, NN * sizeof(int), stream);
    scatter_kernel<<<(NE + 255) / 256, 256, 0, stream>>>(src, dst, cnt, ell);
    gemm1_kernel<<<(NN + 63) / 64, 256, 0, stream>>>(F, W1, P);
    agg1_kernel<<<(NN * 4 + 255) / 256, 256, 0, stream>>>(P, cnt, ell, A1);
    agg2out_kernel<<<(NN * 4 + 255) / 256, 256, 0, stream>>>(A1, b1, cnt, ell, W2, b2, out);
}